// Round 12
// baseline (323.637 us; speedup 1.0000x reference)
//
#include <hip/hip_runtime.h>
#include <stdint.h>
#include <math.h>

// MultHeadAtten: B=1, S=4096, D=768, H=12, Dk=64.
// Q=K=V projections all use Wq/bq (faithful to reference).
// bf16 MFMA; flash attention with swapped QK^T (S^T = mfma(K,Q)) so P stays
// in-lane for PV. NO-max softmax in log2 domain (Q pre-scaled by 0.125*log2e).
// KEY CHANGE (R12): attention reads K/V straight from global into registers
// via FRAGMENT-ORDERED layouts (K''[h][t][f][lane][16B], V'''[h][pair][nv]
// [lane][16B]) built by a relayout kernel -- K/V are L2-resident (1.5 heads
// per XCD ~3MB < 4MB L2), so LDS staging was pure overhead (guide lesson #7).
// No LDS in the main loop; plain C++ loads with explicit A/B double-buffer
// let the compiler emit counted vmcnt waits. LDS used only for the final
// 4-way O combine. Row sums via ones-column MFMA.

#define SQ 4096
#define DM 768
#define NH 12

typedef float f32x4 __attribute__((ext_vector_type(4)));
typedef short bf16x8 __attribute__((ext_vector_type(8)));
typedef unsigned int u32x4 __attribute__((ext_vector_type(4)));
typedef unsigned short ushort_t;

#define MFMA32(a, b, c) __builtin_amdgcn_mfma_f32_16x16x32_bf16((a), (b), (c), 0, 0, 0)

static __device__ __forceinline__ ushort_t f2bf(float f) {
    unsigned int u = __builtin_bit_cast(unsigned int, f);
    u += 0x7fffu + ((u >> 16) & 1u);
    return (ushort_t)(u >> 16);
}

static __device__ __forceinline__ unsigned int cvt_pk_bf16(float a, float b) {
    unsigned int d;
    asm("v_cvt_pk_bf16_f32 %0, %1, %2" : "=v"(d) : "v"(a), "v"(b));
    return d;
}

static __device__ __forceinline__ float exp2_hw(float x) {
    float r;
    asm("v_exp_f32 %0, %1" : "=v"(r) : "v"(x));
    return r;
}

static __device__ __forceinline__ void gload16(const ushort_t* g, ushort_t* l) {
    __builtin_amdgcn_global_load_lds(
        reinterpret_cast<const __attribute__((address_space(1))) unsigned int*>(
            reinterpret_cast<uintptr_t>(g)),
        reinterpret_cast<__attribute__((address_space(3))) unsigned int*>(
            reinterpret_cast<uintptr_t>(l)),
        16, 0, 0);
}

// One fused convert kernel: q,k,v -> xb (3*NE), Wq -> wqb, Wo -> wob.
__global__ __launch_bounds__(256) void cvt_all(
    const float* __restrict__ q, const float* __restrict__ k,
    const float* __restrict__ v, const float* __restrict__ Wq,
    const float* __restrict__ Wo, ushort_t* __restrict__ xb,
    ushort_t* __restrict__ wqb, ushort_t* __restrict__ wob) {
    const int NE4 = (SQ * DM) / 4;
    const int NW4 = (DM * DM) / 4;
    int i = blockIdx.x * 256 + threadIdx.x;
    const float* src;
    ushort_t* dst;
    if (i < NE4) { src = q; dst = xb; }
    else if (i < 2 * NE4) { src = k; dst = xb + SQ * DM; i -= NE4; }
    else if (i < 3 * NE4) { src = v; dst = xb + 2 * SQ * DM; i -= 2 * NE4; }
    else if (i < 3 * NE4 + NW4) { src = Wq; dst = wqb; i -= 3 * NE4; }
    else if (i < 3 * NE4 + 2 * NW4) { src = Wo; dst = wob; i -= 3 * NE4 + NW4; }
    else return;
    float4 x = reinterpret_cast<const float4*>(src)[i];
    ushort4 o;
    o.x = f2bf(x.x); o.y = f2bf(x.y); o.z = f2bf(x.z); o.w = f2bf(x.w);
    reinterpret_cast<ushort4*>(dst)[i] = o;
}

// Fused QK-projection + V^T-projection, one launch (576 blocks).
// Blocks 0..383:  C = xb[0..8192) * Wq^T + bq -> proj (Q rows scaled).
// Blocks 384..575: C = Wq * xv^T + bq(row) -> vt[d][kv] (plain).
__global__ __launch_bounds__(256) void gemm_qkv(
    const ushort_t* __restrict__ xb, const ushort_t* __restrict__ wqb,
    const float* __restrict__ bq, ushort_t* __restrict__ proj,
    ushort_t* __restrict__ vt) {
    __shared__ __align__(16) ushort_t lsA[128 * 64];
    __shared__ __align__(16) ushort_t lsB[128 * 64];
    const int tid = threadIdx.x;
    const int lane = tid & 63;
    const int w = tid >> 6;
    const int wm = w >> 1, wn = w & 1;
    const int g = lane >> 4, li = lane & 15;
    const bool isV = blockIdx.x >= 384;
    const ushort_t* A;
    const ushort_t* B;
    int bm, bn;
    if (!isV) {
        A = xb; B = wqb;
        bm = blockIdx.x / 6; bn = blockIdx.x % 6;
    } else {
        A = wqb; B = xb + 2 * SQ * DM;
        const int b2 = blockIdx.x - 384;
        bm = b2 / 32; bn = b2 % 32;
    }
    const int arow = bm * 128, brow = bn * 128;
    const int sr = lane >> 3;
    const int sc = ((lane & 7) ^ sr) * 8;

    f32x4 acc[4][4] = {};

    for (int kt = 0; kt < 12; ++kt) {
        const int k0 = kt * 64;
        __syncthreads();
#pragma unroll
        for (int c = 0; c < 4; ++c) {
            const int chunk = w * 4 + c;
            const int r = chunk * 8 + sr;
            gload16(A + (size_t)(arow + r) * DM + k0 + sc, lsA + chunk * 512);
            gload16(B + (size_t)(brow + r) * DM + k0 + sc, lsB + chunk * 512);
        }
        __syncthreads();

        bf16x8 af[4][2];
#pragma unroll
        for (int mf = 0; mf < 4; ++mf) {
            const int row = wm * 64 + mf * 16 + li;
#pragma unroll
            for (int ks = 0; ks < 2; ++ks)
                af[mf][ks] = *reinterpret_cast<const bf16x8*>(
                    lsA + row * 64 + ((ks * 32 + g * 8) ^ ((li & 7) << 3)));
        }
#pragma unroll
        for (int nf = 0; nf < 4; ++nf) {
            const int row = wn * 64 + nf * 16 + li;
            bf16x8 b0 = *reinterpret_cast<const bf16x8*>(
                lsB + row * 64 + ((g * 8) ^ ((li & 7) << 3)));
            bf16x8 b1 = *reinterpret_cast<const bf16x8*>(
                lsB + row * 64 + ((32 + g * 8) ^ ((li & 7) << 3)));
#pragma unroll
            for (int mf = 0; mf < 4; ++mf) {
                acc[mf][nf] = MFMA32(af[mf][0], b0, acc[mf][nf]);
                acc[mf][nf] = MFMA32(af[mf][1], b1, acc[mf][nf]);
            }
        }
    }

    // C/D layout: col = li, row = g*4 + reg.
    if (!isV) {
        const float qscale = (arow < 4096) ? 0.18033688011112042f : 1.0f;  // 0.125*log2e
#pragma unroll
        for (int nf = 0; nf < 4; ++nf) {
            const int col = brow + wn * 64 + nf * 16 + li;
            const float bv = bq[col];
#pragma unroll
            for (int mf = 0; mf < 4; ++mf) {
                const int row0 = arow + wm * 64 + mf * 16 + g * 4;
#pragma unroll
                for (int r = 0; r < 4; ++r)
                    proj[(size_t)(row0 + r) * DM + col] = f2bf((acc[mf][nf][r] + bv) * qscale);
            }
        }
    } else {
        // rows = d (bias by row), cols = kv -> vt[d][kv] plain.
        float bv[4][4];
#pragma unroll
        for (int mf = 0; mf < 4; ++mf)
#pragma unroll
            for (int r = 0; r < 4; ++r)
                bv[mf][r] = bq[arow + wm * 64 + mf * 16 + g * 4 + r];
#pragma unroll
        for (int nf = 0; nf < 4; ++nf) {
            const int j = brow + wn * 64 + nf * 16 + li;
#pragma unroll
            for (int mf = 0; mf < 4; ++mf) {
                const int row0 = arow + wm * 64 + mf * 16 + g * 4;
#pragma unroll
                for (int r = 0; r < 4; ++r)
                    vt[(size_t)(row0 + r) * SQ + j] = f2bf(acc[mf][nf][r] + bv[mf][r]);
            }
        }
    }
}

// Relayout into fragment order (16B per thread).
// K'': unit u = ((h*256+t)*2+f)*64 + l holds K[16t+(l&15)][64h+32f+8*(l>>4)+j].
// V''': unit u2 = ((h*128+p)*4+nv)*64 + l holds, for j=0..7 (half=j>>2, c=j&3):
//       V[kv=32p+16*half+4*(l>>4)+c][d=64h+16nv+(l&15)] = vt[d][kv].
__global__ __launch_bounds__(256) void relayout(
    const ushort_t* __restrict__ proj, const ushort_t* __restrict__ vt,
    ushort_t* __restrict__ kpp, ushort_t* __restrict__ vpp) {
    const int u = blockIdx.x * 256 + threadIdx.x;
    if (u < 393216) {
        const int l = u & 63, f = (u >> 6) & 1, t = (u >> 7) & 255, h = u >> 15;
        const ushort_t* s = proj + (size_t)(4096 + 16 * t + (l & 15)) * DM +
                            64 * h + 32 * f + 8 * (l >> 4);
        *reinterpret_cast<bf16x8*>(kpp + (size_t)u * 8) =
            *reinterpret_cast<const bf16x8*>(s);
    } else {
        const int u2 = u - 393216;
        const int l = u2 & 63, nv = (u2 >> 6) & 3, p = (u2 >> 8) & 127, h = u2 >> 15;
        const int dm = 64 * h + 16 * nv + (l & 15);
        const int kv0 = 32 * p + 4 * (l >> 4);
        ushort4 e = *reinterpret_cast<const ushort4*>(vt + (size_t)dm * SQ + kv0);
        ushort4 o = *reinterpret_cast<const ushort4*>(vt + (size_t)dm * SQ + kv0 + 16);
        ushort4* dst = reinterpret_cast<ushort4*>(vpp + (size_t)u2 * 8);
        dst[0] = e;
        dst[1] = o;
    }
}

// Output projection: out[4096][768] fp32 = cc * Wo^T + bo.
__global__ __launch_bounds__(256) void gemm_out(
    const ushort_t* __restrict__ cc, const ushort_t* __restrict__ wob,
    const float* __restrict__ bo, float* __restrict__ outf) {
    __shared__ __align__(16) ushort_t lsA[128 * 64];
    __shared__ __align__(16) ushort_t lsB[128 * 64];
    const int tid = threadIdx.x;
    const int lane = tid & 63;
    const int w = tid >> 6;
    const int wm = w >> 1, wn = w & 1;
    const int g = lane >> 4, li = lane & 15;
    const int bm = blockIdx.x / 6, bn = blockIdx.x % 6;
    const int arow = bm * 128, brow = bn * 128;
    const int sr = lane >> 3;
    const int sc = ((lane & 7) ^ sr) * 8;

    f32x4 acc[4][4] = {};

    for (int kt = 0; kt < 12; ++kt) {
        const int k0 = kt * 64;
        __syncthreads();
#pragma unroll
        for (int c = 0; c < 4; ++c) {
            const int chunk = w * 4 + c;
            const int r = chunk * 8 + sr;
            gload16(cc + (size_t)(arow + r) * DM + k0 + sc, lsA + chunk * 512);
            gload16(wob + (size_t)(brow + r) * DM + k0 + sc, lsB + chunk * 512);
        }
        __syncthreads();

        bf16x8 af[4][2];
#pragma unroll
        for (int mf = 0; mf < 4; ++mf) {
            const int row = wm * 64 + mf * 16 + li;
#pragma unroll
            for (int ks = 0; ks < 2; ++ks)
                af[mf][ks] = *reinterpret_cast<const bf16x8*>(
                    lsA + row * 64 + ((ks * 32 + g * 8) ^ ((li & 7) << 3)));
        }
#pragma unroll
        for (int nf = 0; nf < 4; ++nf) {
            const int row = wn * 64 + nf * 16 + li;
            bf16x8 b0 = *reinterpret_cast<const bf16x8*>(
                lsB + row * 64 + ((g * 8) ^ ((li & 7) << 3)));
            bf16x8 b1 = *reinterpret_cast<const bf16x8*>(
                lsB + row * 64 + ((32 + g * 8) ^ ((li & 7) << 3)));
#pragma unroll
            for (int mf = 0; mf < 4; ++mf) {
                acc[mf][nf] = MFMA32(af[mf][0], b0, acc[mf][nf]);
                acc[mf][nf] = MFMA32(af[mf][1], b1, acc[mf][nf]);
            }
        }
    }

#pragma unroll
    for (int nf = 0; nf < 4; ++nf) {
        const int col = brow + wn * 64 + nf * 16 + li;
        const float bv = bo[col];
#pragma unroll
        for (int mf = 0; mf < 4; ++mf) {
            const int row0 = arow + wm * 64 + mf * 16 + g * 4;
#pragma unroll
            for (int r = 0; r < 4; ++r)
                outf[(size_t)(row0 + r) * DM + col] = acc[mf][nf][r] + bv;
        }
    }
}

// Flash attention, LDS-free main loop. Grid = 768 (XCD-swizzled), 4 waves.
// All waves share 64 q-rows; wave w owns KV quarter = pairs [w*32, w*32+32)
// (pair = 2 tiles of 16 kv). Operands loaded coalesced from fragment-ordered
// K''/V''' into registers, explicit A/B double-buffer (compiler emits counted
// vmcnt). LDS only for the final combine.
__global__ __launch_bounds__(256, 3) void attn_bf16(
    const ushort_t* __restrict__ qk, const ushort_t* __restrict__ kpp,
    const ushort_t* __restrict__ vpp, ushort_t* __restrict__ cc) {
    __shared__ __align__(16) float ob[10240];  // 40KB combine buffer

    const int tid = threadIdx.x, lane = tid & 63, w = tid >> 6;
    const int g = lane >> 4, li = lane & 15;
    const int logical = (blockIdx.x & 7) * 96 + (blockIdx.x >> 3);
    const int h = logical >> 6, qb = logical & 63;

    const ushort_t* kbase = kpp + (size_t)(h * 256 + w * 64) * 1024 + lane * 8;
    const ushort_t* vbase = vpp + (size_t)(h * 128 + w * 32) * 2048 + lane * 8;

    // Q fragments: 64 q-rows shared by all waves.
    bf16x8 qf[4][2];
#pragma unroll
    for (int qh = 0; qh < 4; ++qh)
#pragma unroll
        for (int ks = 0; ks < 2; ++ks)
            qf[qh][ks] = *reinterpret_cast<const bf16x8*>(
                qk + (size_t)(qb * 64 + qh * 16 + li) * DM + h * 64 + ks * 32 + g * 8);

    f32x4 oacc[4][5] = {};  // [qh][nv]; nv=4 = row-sum via ones-MFMA

    const unsigned int one2 = 0x3F803F80u;
    u32x4 onesu = {one2, one2, one2, one2};
    const bf16x8 vones = __builtin_bit_cast(bf16x8, onesu);

#define LOADPAIR(BUF, p)                                                       \
    do {                                                                       \
        const ushort_t* kp_ = kbase + (size_t)(p) * 2048;                      \
        const ushort_t* vp_ = vbase + (size_t)(p) * 2048;                      \
        BUF[0] = *reinterpret_cast<const bf16x8*>(kp_);                        \
        BUF[1] = *reinterpret_cast<const bf16x8*>(kp_ + 512);                  \
        BUF[2] = *reinterpret_cast<const bf16x8*>(kp_ + 1024);                 \
        BUF[3] = *reinterpret_cast<const bf16x8*>(kp_ + 1536);                 \
        BUF[4] = *reinterpret_cast<const bf16x8*>(vp_);                        \
        BUF[5] = *reinterpret_cast<const bf16x8*>(vp_ + 512);                  \
        BUF[6] = *reinterpret_cast<const bf16x8*>(vp_ + 1024);                 \
        BUF[7] = *reinterpret_cast<const bf16x8*>(vp_ + 1536);                 \
    } while (0)

#define COMPUTE(BUF)                                                           \
    do {                                                                       \
        f32x4 Pe_[4], Po_[4];                                                  \
        __builtin_amdgcn_s_setprio(1);                                         \
        _Pragma("unroll") for (int qh = 0; qh < 4; ++qh) {                     \
            f32x4 s = {};                                                      \
            s = MFMA32(BUF[0], qf[qh][0], s);                                  \
            s = MFMA32(BUF[1], qf[qh][1], s);                                  \
            Pe_[qh] = s;                                                       \
        }                                                                      \
        _Pragma("unroll") for (int qh = 0; qh < 4; ++qh) {                     \
            f32x4 s = {};                                                      \
            s = MFMA32(BUF[2], qf[qh][0], s);                                  \
            s = MFMA32(BUF[3], qf[qh][1], s);                                  \
            Po_[qh] = s;                                                       \
        }                                                                      \
        __builtin_amdgcn_s_setprio(0);                                         \
        bf16x8 pa_[4];                                                         \
        _Pragma("unroll") for (int qh = 0; qh < 4; ++qh) {                     \
            u32x4 pu;                                                          \
            pu.x = cvt_pk_bf16(exp2_hw(Pe_[qh][0]), exp2_hw(Pe_[qh][1]));      \
            pu.y = cvt_pk_bf16(exp2_hw(Pe_[qh][2]), exp2_hw(Pe_[qh][3]));      \
            pu.z = cvt_pk_bf16(exp2_hw(Po_[qh][0]), exp2_hw(Po_[qh][1]));      \
            pu.w = cvt_pk_bf16(exp2_hw(Po_[qh][2]), exp2_hw(Po_[qh][3]));      \
            pa_[qh] = __builtin_bit_cast(bf16x8, pu);                          \
        }                                                                      \
        __builtin_amdgcn_s_setprio(1);                                         \
        _Pragma("unroll") for (int nv = 0; nv < 4; ++nv)                       \
            _Pragma("unroll") for (int qh = 0; qh < 4; ++qh)                   \
                oacc[qh][nv] = MFMA32(pa_[qh], BUF[4 + nv], oacc[qh][nv]);     \
        _Pragma("unroll") for (int qh = 0; qh < 4; ++qh)                       \
            oacc[qh][4] = MFMA32(pa_[qh], vones, oacc[qh][4]);                 \
        __builtin_amdgcn_s_setprio(0);                                         \
    } while (0)

    bf16x8 Abuf[8], Bbuf[8];
    LOADPAIR(Abuf, 0);
#pragma unroll 1
    for (int p = 0; p < 30; p += 2) {
        LOADPAIR(Bbuf, p + 1);
        COMPUTE(Abuf);
        LOADPAIR(Abuf, p + 2);
        COMPUTE(Bbuf);
    }
    LOADPAIR(Bbuf, 31);
    COMPUTE(Abuf);
    COMPUTE(Bbuf);
#undef LOADPAIR
#undef COMPUTE

    // 4-way combine (exact: no-max softmax). LDS tree: (2,3)->(0,1)->0.
    __syncthreads();
    if (w >= 2) {
        float* bse = ob + (w - 2) * 5120;
#pragma unroll
        for (int qh = 0; qh < 4; ++qh)
#pragma unroll
            for (int nv = 0; nv < 5; ++nv)
                *reinterpret_cast<f32x4*>(
                    bse + ((qh * 5 + nv) * 64 + lane) * 4) = oacc[qh][nv];
    }
    __syncthreads();
    if (w < 2) {
        const float* bse = ob + w * 5120;
#pragma unroll
        for (int qh = 0; qh < 4; ++qh)
#pragma unroll
            for (int nv = 0; nv < 5; ++nv)
                oacc[qh][nv] += *reinterpret_cast<const f32x4*>(
                    bse + ((qh * 5 + nv) * 64 + lane) * 4);
    }
    __syncthreads();
    if (w == 1) {
#pragma unroll
        for (int qh = 0; qh < 4; ++qh)
#pragma unroll
            for (int nv = 0; nv < 5; ++nv)
                *reinterpret_cast<f32x4*>(
                    ob + ((qh * 5 + nv) * 64 + lane) * 4) = oacc[qh][nv];
    }
    __syncthreads();
    if (w == 0) {
#pragma unroll
        for (int qh = 0; qh < 4; ++qh)
#pragma unroll
            for (int nv = 0; nv < 5; ++nv)
                oacc[qh][nv] += *reinterpret_cast<const f32x4*>(
                    ob + ((qh * 5 + nv) * 64 + lane) * 4);
        // Row sum for q = qh*16 + g*4 + r sits in oacc[qh][4][r].
#pragma unroll
        for (int qh = 0; qh < 4; ++qh) {
            float inv[4];
#pragma unroll
            for (int r = 0; r < 4; ++r) inv[r] = 1.0f / oacc[qh][4][r];
#pragma unroll
            for (int nv = 0; nv < 4; ++nv)
#pragma unroll
                for (int r = 0; r < 4; ++r) {
                    const int row = qb * 64 + qh * 16 + g * 4 + r;
                    const int col = h * 64 + nv * 16 + li;
                    cc[(size_t)row * DM + col] = f2bf(oacc[qh][nv][r] * inv[r]);
                }
        }
    }
}

extern "C" void kernel_launch(void* const* d_in, const int* in_sizes, int n_in,
                              void* d_out, int out_size, void* d_ws, size_t ws_size,
                              hipStream_t stream) {
    const float* q = (const float*)d_in[0];
    const float* k = (const float*)d_in[1];
    const float* v = (const float*)d_in[2];
    const float* Wq = (const float*)d_in[3];
    const float* bq = (const float*)d_in[4];
    const float* Wo = (const float*)d_in[5];
    const float* bo = (const float*)d_in[6];
    float* out = (float*)d_out;

    ushort_t* ws = (ushort_t*)d_ws;
    const int NE = SQ * DM;              // 3145728
    ushort_t* xb = ws;                   // [3*4096][768] bf16 of q,k,v
    ushort_t* wqb = ws + 3 * NE;         // [768][768]
    ushort_t* wob = wqb + DM * DM;       // [768][768]
    ushort_t* proj = wob + DM * DM;      // [8192][768]  Q rows 0.., K rows 4096..
    ushort_t* vt = proj + 2 * NE;        // [768][4096]  V^T plain
    ushort_t* cc = vt + NE;              // [4096][768]  attention concat
    // After gemm_qkv, xb is dead: reuse its space for the fragment-ordered
    // K''/V''' (cvt_all rewrites all of xb every replay -> deterministic).
    ushort_t* kpp = xb;                  // 3,145,728 ushorts
    ushort_t* vpp = xb + NE;             // 3,145,728 ushorts

    const int n4 = 3 * (NE / 4) + 2 * ((DM * DM) / 4);
    cvt_all<<<(n4 + 255) / 256, 256, 0, stream>>>(q, k, v, Wq, Wo, xb, wqb, wob);

    // Fused Q/K projection (384 blocks) + V^T projection (192 blocks).
    gemm_qkv<<<576, 256, 0, stream>>>(xb, wqb, bq, proj, vt);

    // Fragment-order K and V (786432 threads).
    relayout<<<3072, 256, 0, stream>>>(proj, vt, kpp, vpp);

    // Attention: 768 blocks, 256 threads, LDS-free main loop.
    attn_bf16<<<NH * (SQ / 64), 256, 0, stream>>>(proj, kpp, vpp, cc);

    // Output projection: M = 4096, fp32 out.
    gemm_out<<<(SQ / 128) * 6, 256, 0, stream>>>(cc, wob, bo, out);
}

// Round 13
// 134.081 us; speedup vs baseline: 2.4137x; 2.4137x over previous
//
#include <hip/hip_runtime.h>
#include <stdint.h>
#include <math.h>

// MultHeadAtten: B=1, S=4096, D=768, H=12, Dk=64.
// Q=K=V projections all use Wq/bq (faithful to reference).
// bf16 MFMA; flash attention with swapped QK^T (S^T = mfma(K,Q)) so P stays
// in-lane for PV. V^T computed directly by swapped-operand GEMM with columns
// bit-permuted (slot convention: pos = bits {b4,b3,b2}->{b3,b2,b4}) so the
// PV B-operand is one contiguous read. NO-max softmax (scores bounded;
// softmax shift-invariant) in log2 domain: Q pre-scaled by 0.125*log2(e).
// Attn (R8 structure, measured 76.9us): 4 waves = 2 wave-pairs; pair p owns
// KV rows [p*2048,(p+1)*2048), KVBLK=32 double-buffered (32KB LDS -> 3
// blocks/CU = 12 waves/CU). V LDS slot-swizzle f(d)=(d>>1)&3 -> 2-way max
// bank aliasing (free). Exact combine at end (O=O0+O1, l=l0+l1).
// R13 consolidation: fused QK-proj + V^T-proj into one 576-block launch.

#define SQ 4096
#define DM 768
#define NH 12

typedef float f32x4 __attribute__((ext_vector_type(4)));
typedef short bf16x8 __attribute__((ext_vector_type(8)));
typedef unsigned int u32x4 __attribute__((ext_vector_type(4)));
typedef unsigned short ushort_t;

#define MFMA32(a, b, c) __builtin_amdgcn_mfma_f32_16x16x32_bf16((a), (b), (c), 0, 0, 0)

static __device__ __forceinline__ ushort_t f2bf(float f) {
    unsigned int u = __builtin_bit_cast(unsigned int, f);
    u += 0x7fffu + ((u >> 16) & 1u);
    return (ushort_t)(u >> 16);
}

// pack 2 f32 -> 2 bf16 in one u32 (lo = a, hi = b), RNE.
static __device__ __forceinline__ unsigned int cvt_pk_bf16(float a, float b) {
    unsigned int d;
    asm("v_cvt_pk_bf16_f32 %0, %1, %2" : "=v"(d) : "v"(a), "v"(b));
    return d;
}

// native HW exp2 (v_exp_f32 computes 2^x): single TRANS instruction.
static __device__ __forceinline__ float exp2_hw(float x) {
    float r;
    asm("v_exp_f32 %0, %1" : "=v"(r) : "v"(x));
    return r;
}

// global -> LDS async 16B/lane. LDS dest is wave-uniform base; HW writes
// lane i at base + 16*i.
static __device__ __forceinline__ void gload16(const ushort_t* g, ushort_t* l) {
    __builtin_amdgcn_global_load_lds(
        reinterpret_cast<const __attribute__((address_space(1))) unsigned int*>(
            reinterpret_cast<uintptr_t>(g)),
        reinterpret_cast<__attribute__((address_space(3))) unsigned int*>(
            reinterpret_cast<uintptr_t>(l)),
        16, 0, 0);
}

// One fused convert kernel: q,k,v -> xb (3*NE), Wq -> wqb, Wo -> wob.
__global__ __launch_bounds__(256) void cvt_all(
    const float* __restrict__ q, const float* __restrict__ k,
    const float* __restrict__ v, const float* __restrict__ Wq,
    const float* __restrict__ Wo, ushort_t* __restrict__ xb,
    ushort_t* __restrict__ wqb, ushort_t* __restrict__ wob) {
    const int NE4 = (SQ * DM) / 4;
    const int NW4 = (DM * DM) / 4;
    int i = blockIdx.x * 256 + threadIdx.x;
    const float* src;
    ushort_t* dst;
    if (i < NE4) { src = q; dst = xb; }
    else if (i < 2 * NE4) { src = k; dst = xb + SQ * DM; i -= NE4; }
    else if (i < 3 * NE4) { src = v; dst = xb + 2 * SQ * DM; i -= 2 * NE4; }
    else if (i < 3 * NE4 + NW4) { src = Wq; dst = wqb; i -= 3 * NE4; }
    else if (i < 3 * NE4 + 2 * NW4) { src = Wo; dst = wob; i -= 3 * NE4 + NW4; }
    else return;
    float4 x = reinterpret_cast<const float4*>(src)[i];
    ushort4 o;
    o.x = f2bf(x.x); o.y = f2bf(x.y); o.z = f2bf(x.z); o.w = f2bf(x.w);
    reinterpret_cast<ushort4*>(dst)[i] = o;
}

// Fused QK-projection + V^T-projection, one launch (576 blocks).
// Blocks 0..383:  C = xb[0..8192) * Wq^T + bq -> proj (Q rows scaled by
//                 0.125*log2e, K rows plain).
// Blocks 384..575: C = Wq * xv^T + bq(row) -> vt[d][perm(kv)], perm = bits
//                 {b4,b3,b2}->{b3,b2,b4} (R8 slot convention).
__global__ __launch_bounds__(256) void gemm_qkv(
    const ushort_t* __restrict__ xb, const ushort_t* __restrict__ wqb,
    const float* __restrict__ bq, ushort_t* __restrict__ proj,
    ushort_t* __restrict__ vt) {
    __shared__ __align__(16) ushort_t lsA[128 * 64];
    __shared__ __align__(16) ushort_t lsB[128 * 64];
    const int tid = threadIdx.x;
    const int lane = tid & 63;
    const int w = tid >> 6;
    const int wm = w >> 1, wn = w & 1;
    const int g = lane >> 4, li = lane & 15;
    const bool isV = blockIdx.x >= 384;
    const ushort_t* A;
    const ushort_t* B;
    int bm, bn;
    if (!isV) {
        A = xb; B = wqb;
        bm = blockIdx.x / 6; bn = blockIdx.x % 6;
    } else {
        A = wqb; B = xb + 2 * SQ * DM;
        const int b2 = blockIdx.x - 384;
        bm = b2 / 32; bn = b2 % 32;
    }
    const int arow = bm * 128, brow = bn * 128;
    const int sr = lane >> 3;
    const int sc = ((lane & 7) ^ sr) * 8;

    f32x4 acc[4][4] = {};

    for (int kt = 0; kt < 12; ++kt) {
        const int k0 = kt * 64;
        __syncthreads();
#pragma unroll
        for (int c = 0; c < 4; ++c) {
            const int chunk = w * 4 + c;
            const int r = chunk * 8 + sr;
            gload16(A + (size_t)(arow + r) * DM + k0 + sc, lsA + chunk * 512);
            gload16(B + (size_t)(brow + r) * DM + k0 + sc, lsB + chunk * 512);
        }
        __syncthreads();

        bf16x8 af[4][2];
#pragma unroll
        for (int mf = 0; mf < 4; ++mf) {
            const int row = wm * 64 + mf * 16 + li;
#pragma unroll
            for (int ks = 0; ks < 2; ++ks)
                af[mf][ks] = *reinterpret_cast<const bf16x8*>(
                    lsA + row * 64 + ((ks * 32 + g * 8) ^ ((li & 7) << 3)));
        }
#pragma unroll
        for (int nf = 0; nf < 4; ++nf) {
            const int row = wn * 64 + nf * 16 + li;
            bf16x8 b0 = *reinterpret_cast<const bf16x8*>(
                lsB + row * 64 + ((g * 8) ^ ((li & 7) << 3)));
            bf16x8 b1 = *reinterpret_cast<const bf16x8*>(
                lsB + row * 64 + ((32 + g * 8) ^ ((li & 7) << 3)));
#pragma unroll
            for (int mf = 0; mf < 4; ++mf) {
                acc[mf][nf] = MFMA32(af[mf][0], b0, acc[mf][nf]);
                acc[mf][nf] = MFMA32(af[mf][1], b1, acc[mf][nf]);
            }
        }
    }

    // Epilogue. C/D layout: col = li, row = g*4 + reg.
    if (!isV) {
        const float qscale = (arow < 4096) ? 0.18033688011112042f : 1.0f;  // 0.125*log2e
#pragma unroll
        for (int nf = 0; nf < 4; ++nf) {
            const int col = brow + wn * 64 + nf * 16 + li;
            const float bv = bq[col];
#pragma unroll
            for (int mf = 0; mf < 4; ++mf) {
                const int row0 = arow + wm * 64 + mf * 16 + g * 4;
#pragma unroll
                for (int r = 0; r < 4; ++r)
                    proj[(size_t)(row0 + r) * DM + col] = f2bf((acc[mf][nf][r] + bv) * qscale);
            }
        }
    } else {
        // rows = d (bias by ROW), cols = kv -> vt[d][perm(kv)].
        float bv[4][4];
#pragma unroll
        for (int mf = 0; mf < 4; ++mf)
#pragma unroll
            for (int r = 0; r < 4; ++r)
                bv[mf][r] = bq[arow + wm * 64 + mf * 16 + g * 4 + r];
#pragma unroll
        for (int nf = 0; nf < 4; ++nf) {
            const int j = brow + wn * 64 + nf * 16 + li;
            const int pos = (j & ~31) | ((j & 0xC) << 1) | (((j >> 4) & 1) << 2) | (j & 3);
#pragma unroll
            for (int mf = 0; mf < 4; ++mf) {
                const int row0 = arow + wm * 64 + mf * 16 + g * 4;
#pragma unroll
                for (int r = 0; r < 4; ++r)
                    vt[(size_t)(row0 + r) * SQ + pos] = f2bf(acc[mf][nf][r] + bv[mf][r]);
            }
        }
    }
}

// Output projection: out[4096][768] fp32 = cc * Wo^T + bo.
__global__ __launch_bounds__(256) void gemm_out(
    const ushort_t* __restrict__ cc, const ushort_t* __restrict__ wob,
    const float* __restrict__ bo, float* __restrict__ outf) {
    __shared__ __align__(16) ushort_t lsA[128 * 64];
    __shared__ __align__(16) ushort_t lsB[128 * 64];
    const int tid = threadIdx.x;
    const int lane = tid & 63;
    const int w = tid >> 6;
    const int wm = w >> 1, wn = w & 1;
    const int g = lane >> 4, li = lane & 15;
    const int bm = blockIdx.x / 6, bn = blockIdx.x % 6;
    const int arow = bm * 128, brow = bn * 128;
    const int sr = lane >> 3;
    const int sc = ((lane & 7) ^ sr) * 8;

    f32x4 acc[4][4] = {};

    for (int kt = 0; kt < 12; ++kt) {
        const int k0 = kt * 64;
        __syncthreads();
#pragma unroll
        for (int c = 0; c < 4; ++c) {
            const int chunk = w * 4 + c;
            const int r = chunk * 8 + sr;
            gload16(cc + (size_t)(arow + r) * DM + k0 + sc, lsA + chunk * 512);
            gload16(wob + (size_t)(brow + r) * DM + k0 + sc, lsB + chunk * 512);
        }
        __syncthreads();

        bf16x8 af[4][2];
#pragma unroll
        for (int mf = 0; mf < 4; ++mf) {
            const int row = wm * 64 + mf * 16 + li;
#pragma unroll
            for (int ks = 0; ks < 2; ++ks)
                af[mf][ks] = *reinterpret_cast<const bf16x8*>(
                    lsA + row * 64 + ((ks * 32 + g * 8) ^ ((li & 7) << 3)));
        }
#pragma unroll
        for (int nf = 0; nf < 4; ++nf) {
            const int row = wn * 64 + nf * 16 + li;
            bf16x8 b0 = *reinterpret_cast<const bf16x8*>(
                lsB + row * 64 + ((g * 8) ^ ((li & 7) << 3)));
            bf16x8 b1 = *reinterpret_cast<const bf16x8*>(
                lsB + row * 64 + ((32 + g * 8) ^ ((li & 7) << 3)));
#pragma unroll
            for (int mf = 0; mf < 4; ++mf) {
                acc[mf][nf] = MFMA32(af[mf][0], b0, acc[mf][nf]);
                acc[mf][nf] = MFMA32(af[mf][1], b1, acc[mf][nf]);
            }
        }
    }

#pragma unroll
    for (int nf = 0; nf < 4; ++nf) {
        const int col = brow + wn * 64 + nf * 16 + li;
        const float bv = bo[col];
#pragma unroll
        for (int mf = 0; mf < 4; ++mf) {
            const int row0 = arow + wm * 64 + mf * 16 + g * 4;
#pragma unroll
            for (int r = 0; r < 4; ++r)
                outf[(size_t)(row0 + r) * DM + col] = acc[mf][nf][r] + bv;
        }
    }
}

// Flash attention (R8 structure, measured 76.9us): swapped-QK, no-max
// softmax, P in-lane, intra-block KV-split.
// Grid = 768 blocks (XCD-swizzled), 256 threads = 4 waves = 2 pairs.
// Pair p: KV rows [p*2048,(p+1)*2048), KVBLK=32, double-buffered.
// Wave-in-pair wp owns q-rows qb*64 + wp*32 + (0..31).
__global__ __launch_bounds__(256) void attn_bf16(
    const ushort_t* __restrict__ qk, const ushort_t* __restrict__ vtb,
    ushort_t* __restrict__ cc) {
    __shared__ __align__(16) ushort_t kl[2][2][32 * 64];  // [pair][buf]
    __shared__ __align__(16) ushort_t vl[2][2][64 * 32];  // [pair][buf]

    const int tid = threadIdx.x, lane = tid & 63, w = tid >> 6;  // w 0..3
    const int wp = w & 1, p = w >> 1;
    const int g = lane >> 4, li = lane & 15;
    // XCD swizzle: 768 = 8 * 96; head-major logical order.
    const int logical = (blockIdx.x & 7) * 96 + (blockIdx.x >> 3);
    const int h = logical >> 6, qb = logical & 63;
    // K staging: 1KB chunks of 8 rows x 128B; source col pre-swizzled.
    const int sr = lane >> 3;
    const int sc = ((lane & 7) ^ sr) * 8;
    // V staging: 1KB chunks of 16 d-rows x 64B; slot swizzle f(d)=(d>>1)&3
    // (2 lanes/bank-position on read -> conflict-free).
    const int vdr = lane >> 2;                        // d-row within chunk
    const int vsc = ((lane & 3) ^ ((lane >> 3) & 3)) * 8;  // swizzled col

    const ushort_t* Kb = qk + (size_t)(4096 + p * 2048) * DM + (size_t)h * 64;
    const ushort_t* Vb = vtb + (size_t)(h * 64) * SQ + p * 2048;

    // Q fragments hoisted (reused over all KV tiles).
    bf16x8 qf[2][2];
#pragma unroll
    for (int qh = 0; qh < 2; ++qh)
#pragma unroll
        for (int ks = 0; ks < 2; ++ks)
            qf[qh][ks] = *reinterpret_cast<const bf16x8*>(
                qk + (size_t)(qb * 64 + wp * 32 + qh * 16 + li) * DM + h * 64 + ks * 32 + g * 8);

    f32x4 oacc[2][4] = {};
    float lsum0 = 0.f, lsum1 = 0.f;

    // Prologue: stage tile 0 into buf 0 (pair-private; 2 waves per pair).
#pragma unroll
    for (int c = 0; c < 2; ++c) {
        const int ch = wp * 2 + c;  // 0..3
        gload16(Kb + (size_t)(ch * 8 + sr) * DM + sc, &kl[p][0][ch * 512]);
        gload16(Vb + (size_t)(ch * 16 + vdr) * SQ + vsc, &vl[p][0][ch * 512]);
    }
    __syncthreads();

    // One KV step (KVBLK=32). kp/vp/kn/vn loop-invariant LDS pointers.
#define STEP(kp, vp, kn, vn, kvn)                                              \
    do {                                                                       \
        if ((kvn) < 64) {                                                      \
            const int kvo = (kvn) * 32;                                        \
            _Pragma("unroll") for (int c = 0; c < 2; ++c) {                    \
                const int ch = wp * 2 + c;                                     \
                gload16(Kb + (size_t)(kvo + ch * 8 + sr) * DM + sc,            \
                        &(kn)[ch * 512]);                                      \
                gload16(Vb + (size_t)(ch * 16 + vdr) * SQ + kvo + vsc,         \
                        &(vn)[ch * 512]);                                      \
            }                                                                  \
        }                                                                      \
        f32x4 sf[2][2] = {};                                                   \
        __builtin_amdgcn_s_setprio(1);                                         \
        _Pragma("unroll") for (int nf = 0; nf < 2; ++nf) {                     \
            const int row = nf * 16 + li;                                      \
            bf16x8 kb0 = *reinterpret_cast<const bf16x8*>(                     \
                (kp) + row * 64 + ((g * 8) ^ ((li & 7) << 3)));                \
            bf16x8 kb1 = *reinterpret_cast<const bf16x8*>(                     \
                (kp) + row * 64 + ((32 + g * 8) ^ ((li & 7) << 3)));           \
            _Pragma("unroll") for (int qh = 0; qh < 2; ++qh) {                 \
                sf[qh][nf] = MFMA32(kb0, qf[qh][0], sf[qh][nf]);               \
                sf[qh][nf] = MFMA32(kb1, qf[qh][1], sf[qh][nf]);               \
            }                                                                  \
        }                                                                      \
        __builtin_amdgcn_s_setprio(0);                                         \
        _Pragma("unroll") for (int qh = 0; qh < 2; ++qh)                       \
            _Pragma("unroll") for (int nf = 0; nf < 2; ++nf) {                 \
                f32x4 pe;                                                      \
                _Pragma("unroll") for (int r = 0; r < 4; ++r)                  \
                    pe[r] = exp2_hw(sf[qh][nf][r]);                            \
                sf[qh][nf] = pe;                                               \
                const float ps = (pe[0] + pe[1]) + (pe[2] + pe[3]);            \
                if (qh == 0) lsum0 += ps; else lsum1 += ps;                    \
            }                                                                  \
        __builtin_amdgcn_s_setprio(1);                                         \
        bf16x8 pa[2];                                                          \
        _Pragma("unroll") for (int qh = 0; qh < 2; ++qh) {                     \
            u32x4 pu;                                                          \
            pu.x = cvt_pk_bf16(sf[qh][0][0], sf[qh][0][1]);                    \
            pu.y = cvt_pk_bf16(sf[qh][0][2], sf[qh][0][3]);                    \
            pu.z = cvt_pk_bf16(sf[qh][1][0], sf[qh][1][1]);                    \
            pu.w = cvt_pk_bf16(sf[qh][1][2], sf[qh][1][3]);                    \
            pa[qh] = __builtin_bit_cast(bf16x8, pu);                           \
        }                                                                      \
        _Pragma("unroll") for (int nv = 0; nv < 4; ++nv) {                     \
            const int vrow = nv * 16 + li;                                     \
            bf16x8 vb = *reinterpret_cast<const bf16x8*>(                      \
                (vp) + vrow * 32 + ((g ^ ((li >> 1) & 3)) * 8));               \
            oacc[0][nv] = MFMA32(pa[0], vb, oacc[0][nv]);                      \
            oacc[1][nv] = MFMA32(pa[1], vb, oacc[1][nv]);                      \
        }                                                                      \
        __builtin_amdgcn_s_setprio(0);                                         \
        __syncthreads();                                                       \
    } while (0)

    {
        ushort_t* k0p = &kl[p][0][0];
        ushort_t* v0p = &vl[p][0][0];
        ushort_t* k1p = &kl[p][1][0];
        ushort_t* v1p = &vl[p][1][0];
#pragma unroll 1
        for (int t = 0; t < 32; ++t) {
            STEP(k0p, v0p, k1p, v1p, 2 * t + 1);
            STEP(k1p, v1p, k0p, v0p, 2 * t + 2);
        }
    }
#undef STEP

    // Combine the two KV halves (exact: no-max softmax). Reuse kl/vl LDS.
    float* ob = reinterpret_cast<float*>(&kl[0][0][0]);   // 16KB O partials
    float* lsb = ob + 4096;                               // 1KB lsum partials
    if (p == 1) {
#pragma unroll
        for (int qh = 0; qh < 2; ++qh) {
#pragma unroll
            for (int nv = 0; nv < 4; ++nv)
                *reinterpret_cast<f32x4*>(
                    ob + (((wp * 2 + qh) * 4 + nv) * 64 + lane) * 4) = oacc[qh][nv];
            lsb[(wp * 2 + qh) * 64 + lane] = (qh == 0) ? lsum0 : lsum1;
        }
    }
    __syncthreads();
    if (p == 0) {
        lsum0 += lsb[(wp * 2 + 0) * 64 + lane];
        lsum1 += lsb[(wp * 2 + 1) * 64 + lane];
#pragma unroll
        for (int qh = 0; qh < 2; ++qh)
#pragma unroll
            for (int nv = 0; nv < 4; ++nv) {
                f32x4 o = *reinterpret_cast<const f32x4*>(
                    ob + (((wp * 2 + qh) * 4 + nv) * 64 + lane) * 4);
                oacc[qh][nv] += o;
            }

        // Row sums live at lanes with same li (q=li): reduce across 4 groups,
        // fetch inv for q = g*4+r via shfl from lanes 0..15, write concat.
#pragma unroll
        for (int qh = 0; qh < 2; ++qh) {
            float s = (qh == 0) ? lsum0 : lsum1;
            s += __shfl_xor(s, 16);
            s += __shfl_xor(s, 32);
            float inv[4];
            const int gbase = g << 2;
#pragma unroll
            for (int r = 0; r < 4; ++r)
                inv[r] = 1.0f / __shfl(s, gbase + r);
#pragma unroll
            for (int nv = 0; nv < 4; ++nv)
#pragma unroll
                for (int r = 0; r < 4; ++r) {
                    const int row = qb * 64 + wp * 32 + qh * 16 + g * 4 + r;
                    const int col = h * 64 + nv * 16 + li;
                    cc[(size_t)row * DM + col] = f2bf(oacc[qh][nv][r] * inv[r]);
                }
        }
    }
}

extern "C" void kernel_launch(void* const* d_in, const int* in_sizes, int n_in,
                              void* d_out, int out_size, void* d_ws, size_t ws_size,
                              hipStream_t stream) {
    const float* q = (const float*)d_in[0];
    const float* k = (const float*)d_in[1];
    const float* v = (const float*)d_in[2];
    const float* Wq = (const float*)d_in[3];
    const float* bq = (const float*)d_in[4];
    const float* Wo = (const float*)d_in[5];
    const float* bo = (const float*)d_in[6];
    float* out = (float*)d_out;

    ushort_t* ws = (ushort_t*)d_ws;
    const int NE = SQ * DM;              // 3145728
    ushort_t* xb = ws;                   // [3*4096][768] bf16 of q,k,v
    ushort_t* wqb = ws + 3 * NE;         // [768][768]
    ushort_t* wob = wqb + DM * DM;       // [768][768]
    ushort_t* proj = wob + DM * DM;      // [8192][768]  Q rows 0.., K rows 4096..
    ushort_t* vt = proj + 2 * NE;        // [768][4096]  V^T, columns permuted
    ushort_t* cc = vt + NE;              // [4096][768]  attention concat

    // Fused converts: 3*NE/4 + 2*DM*DM/4 float4s.
    const int n4 = 3 * (NE / 4) + 2 * ((DM * DM) / 4);
    cvt_all<<<(n4 + 255) / 256, 256, 0, stream>>>(q, k, v, Wq, Wo, xb, wqb, wob);

    // Fused Q/K projection (384 blocks) + V^T projection (192 blocks).
    gemm_qkv<<<576, 256, 0, stream>>>(xb, wqb, bq, proj, vt);

    // Attention: 768 blocks, 256 threads (2 pairs x 2 waves x 32 q-rows).
    attn_bf16<<<NH * (SQ / 64), 256, 0, stream>>>(proj, vt, cc);

    // Output projection: M = 4096, fp32 out.
    gemm_out<<<(SQ / 128) * 6, 256, 0, stream>>>(cc, wob, bo, out);
}